// Round 2
// baseline (1124.240 us; speedup 1.0000x reference)
//
#include <hip/hip_runtime.h>
#include <hip/hip_bf16.h>

// ===========================================================================
// EEGRCformer forward on MI355X. ALL tensors are float32 (round-1 evidence:
// threshold = 2% * max|ref| -> fp32 path; bf16 interpretation gave NaN).
// ws layout (floats): feats[128*62*504] | pf[128*62*128] | gsums[15] |
//                     gcnt[5] | assign[62 ints]
// ===========================================================================

typedef unsigned int u32;

#define N_SIG   7936          // 128*62
#define FDIM    504           // 36*14
#define DM      128

__device__ __constant__ int band_of_c[46] = {
    -1, 0,0,0, 1,1,1,1, 2,2,2,2, 3,3,3,3, 4,4,4,4,
    5,5,5,5,5,5,5,5,5,5,
    6,6,6,6,6,6,6,6,6,6,6,6,6,6,6, -1};
__device__ __constant__ float bandcnt_c[7] = {3.f,4.f,4.f,4.f,4.f,10.f,15.f};

// block reduce of (a,b) over 128 threads (2 waves); scr must be >=4 floats
static __device__ __forceinline__ void bred2(float& a, float& b, volatile float* scr, int tid){
    #pragma unroll
    for (int off = 32; off > 0; off >>= 1){
        a += __shfl_down(a, off, 64);
        b += __shfl_down(b, off, 64);
    }
    if ((tid & 63) == 0){ scr[tid>>6] = a; scr[2 + (tid>>6)] = b; }
    __syncthreads();
    a = scr[0] + scr[1];
    b = scr[2] + scr[3];
    __syncthreads();
}

// ---------------------------------------------------------------------------
// Kernel A: windowed DFT -> band PSD + DE -> per-signal z-norm -> feats
// 1984 blocks x 256 threads, 4 signals per block.
// ---------------------------------------------------------------------------
__global__ __launch_bounds__(256) void feat_kernel(
        const float* __restrict__ x, float* __restrict__ feats,
        float* __restrict__ gsums, float* __restrict__ gcnt)
{
    __shared__ float xs[4*2004];     // zero-padded signal rows
    __shared__ float bc[12*252];     // hann-folded cos basis (12 bins padded)
    __shared__ float bs[12*252];     // hann-folded sin basis
    __shared__ float psum[4*36*7];   // band power sums

    const int tid = threadIdx.x;
    const int blk = blockIdx.x;
    const int sig0 = blk * 4;

    if (blk == 0 && tid < 20){
        if (tid < 15) gsums[tid] = 0.f; else gcnt[tid-15] = 0.f;
    }

    for (int idx = tid; idx < 4*2004; idx += 256){
        int s = idx / 2004, n = idx - s*2004;
        float v = 0.f;
        if (n < 2000) v = x[(size_t)(sig0+s)*2000 + n];
        xs[idx] = v;
    }
    for (int i = tid; i < 4*36*7; i += 256) psum[i] = 0.f;
    __syncthreads();

    const float TPO = 0.025132741228718345f; // 2*pi/250

    for (int cc = 0; cc < 4; ++cc){
        const int k0 = 1 + cc*11;
        // build basis (12 rows of 252, rows >=11 are compute-discard pad)
        for (int idx = tid; idx < 12*252; idx += 256){
            int kk = idx / 252, n = idx - kk*252;
            float vc = 0.f, vs = 0.f;
            if (n < 250){
                int k = k0 + kk;
                int m = (k*n) % 250;        // exact reduction
                float th = (float)m * TPO;
                float sn, csn; sincosf(th, &sn, &csn);
                float hw = 0.5f*(1.f - cosf((float)n * TPO));
                vc = hw*csn; vs = hw*sn;
            }
            bc[idx] = vc; bs[idx] = vs;
        }
        __syncthreads();

        if (tid < 216){
            const int kp = tid / 36;           // 0..5 -> bins 2kp, 2kp+1
            const int sw = tid - kp*36;
            const int s  = sw / 9;
            const int wg = sw - s*9;
            const int w0 = wg * 4;
            const int ka = 2*kp, kb = 2*kp + 1;

            const float4* bca = (const float4*)(bc + ka*252);
            const float4* bsa = (const float4*)(bs + ka*252);
            const float4* bcb = (const float4*)(bc + kb*252);
            const float4* bsb = (const float4*)(bs + kb*252);
            const float* xb = xs + s*2004 + 50*w0;

            float aca[4] = {0,0,0,0}, asa[4] = {0,0,0,0};
            float acb[4] = {0,0,0,0}, asb[4] = {0,0,0,0};

            for (int q = 0; q < 63; ++q){
                float4 ca = bca[q], sa = bsa[q];
                float4 cb = bcb[q], sb = bsb[q];
                #pragma unroll
                for (int w = 0; w < 4; ++w){
                    const float2* xp = (const float2*)(xb + 50*w + 4*q);
                    float2 u0 = xp[0], u1 = xp[1];
                    float x0 = u0.x, x1 = u0.y, x2 = u1.x, x3 = u1.y;
                    aca[w] = fmaf(x0, ca.x, aca[w]); aca[w] = fmaf(x1, ca.y, aca[w]);
                    aca[w] = fmaf(x2, ca.z, aca[w]); aca[w] = fmaf(x3, ca.w, aca[w]);
                    asa[w] = fmaf(x0, sa.x, asa[w]); asa[w] = fmaf(x1, sa.y, asa[w]);
                    asa[w] = fmaf(x2, sa.z, asa[w]); asa[w] = fmaf(x3, sa.w, asa[w]);
                    acb[w] = fmaf(x0, cb.x, acb[w]); acb[w] = fmaf(x1, cb.y, acb[w]);
                    acb[w] = fmaf(x2, cb.z, acb[w]); acb[w] = fmaf(x3, cb.w, acb[w]);
                    asb[w] = fmaf(x0, sb.x, asb[w]); asb[w] = fmaf(x1, sb.y, asb[w]);
                    asb[w] = fmaf(x2, sb.z, asb[w]); asb[w] = fmaf(x3, sb.w, asb[w]);
                }
            }
            const int bA = band_of_c[k0 + ka];
            #pragma unroll
            for (int w = 0; w < 4; ++w){
                float pa = (aca[w]*aca[w] + asa[w]*asa[w]) * (1.0f/250.0f);
                atomicAdd(&psum[(s*36 + w0 + w)*7 + bA], pa);
            }
            if (kb < 11){
                const int bB = band_of_c[k0 + kb];
                #pragma unroll
                for (int w = 0; w < 4; ++w){
                    float pb = (acb[w]*acb[w] + asb[w]*asb[w]) * (1.0f/250.0f);
                    atomicAdd(&psum[(s*36 + w0 + w)*7 + bB], pb);
                }
            }
        }
        __syncthreads();
    }

    // per-signal normalization: one wave per signal
    {
        const int s = tid >> 6, lane = tid & 63;
        float s1p=0,s2p=0,s1d=0,s2d=0;
        for (int e = lane; e < 252; e += 64){
            int bi = e % 7;
            float psd = psum[s*252 + e] / bandcnt_c[bi];
            float de  = 0.5f * logf(17.079468445347134f*psd + 1e-9f);
            s1p += psd; s2p += psd*psd; s1d += de; s2d += de*de;
        }
        #pragma unroll
        for (int off = 32; off > 0; off >>= 1){
            s1p += __shfl_down(s1p, off, 64); s2p += __shfl_down(s2p, off, 64);
            s1d += __shfl_down(s1d, off, 64); s2d += __shfl_down(s2d, off, 64);
        }
        s1p = __shfl(s1p, 0, 64); s2p = __shfl(s2p, 0, 64);
        s1d = __shfl(s1d, 0, 64); s2d = __shfl(s2d, 0, 64);
        float mp = s1p / 252.f;
        float vp = fmaxf((s2p - 252.f*mp*mp) / 251.f, 0.f);
        float sp = sqrtf(vp) + 1e-9f;
        float md = s1d / 252.f;
        float vd = fmaxf((s2d - 252.f*md*md) / 251.f, 0.f);
        float sd = sqrtf(vd) + 1e-9f;

        float* ob = feats + (size_t)(sig0 + s) * FDIM;
        for (int e = lane; e < 252; e += 64){
            int w = e / 7, bi = e - w*7;
            float psd = psum[s*252 + e] / bandcnt_c[bi];
            float de  = 0.5f * logf(17.079468445347134f*psd + 1e-9f);
            ob[w*14 + bi]     = (psd - mp) / sp;
            ob[w*14 + 7 + bi] = (de  - md) / sd;
        }
    }
}

// ---------------------------------------------------------------------------
// Kernel B: per-batch 62x62 feature distances -> FPS(5) -> temp assign ->
// atomic accumulate pos sums/counts. 128 blocks x 256 threads.
// ---------------------------------------------------------------------------
__global__ __launch_bounds__(256) void cluster_kernel(
        const float* __restrict__ feats, const float* __restrict__ pos_emb,
        float* __restrict__ gsums, float* __restrict__ gcnt)
{
    __shared__ float Fc[62*130];
    __shared__ float Dm[62*62];
    __shared__ float mdv[62];
    __shared__ float rsv[62];
    __shared__ int   seli[5];
    __shared__ float ccen[5][3];

    const int tid = threadIdx.x;
    const int b   = blockIdx.x;

    for (int i = tid; i < 3844; i += 256) Dm[i] = 0.f;
    __syncthreads();

    for (int ch = 0; ch < 4; ++ch){
        for (int i = tid; i < 62*126; i += 256){
            int r = i / 126, dc = i - r*126;
            Fc[r*130 + dc] = feats[((size_t)b*62 + r)*FDIM + ch*126 + dc];
        }
        __syncthreads();
        for (int e = tid; e < 3844; e += 256){
            int i = e / 62, j = e - i*62;
            const float2* ri = (const float2*)(Fc + i*130);
            const float2* rj = (const float2*)(Fc + j*130);
            float acc = 0.f;
            for (int t = 0; t < 63; ++t){
                float2 a = ri[t], c = rj[t];
                float d0 = a.x - c.x, d1 = a.y - c.y;
                acc = fmaf(d0, d0, acc); acc = fmaf(d1, d1, acc);
            }
            Dm[e] += acc;
        }
        __syncthreads();
    }
    for (int e = tid; e < 3844; e += 256) Dm[e] = sqrtf(Dm[e]);
    __syncthreads();

    if (tid < 62){ float s = 0.f; for (int j = 0; j < 62; ++j) s += Dm[tid*62 + j]; rsv[tid] = s; }
    __syncthreads();
    if (tid == 0){
        int bi = 0; float bv = rsv[0];
        for (int i = 1; i < 62; ++i) if (rsv[i] > bv){ bv = rsv[i]; bi = i; }
        seli[0] = bi;
    }
    __syncthreads();
    if (tid < 62) mdv[tid] = Dm[seli[0]*62 + tid];
    __syncthreads();
    for (int it = 1; it < 5; ++it){
        if (tid == 0){
            int bi = 0; float bv = mdv[0];
            for (int i = 1; i < 62; ++i) if (mdv[i] > bv){ bv = mdv[i]; bi = i; }
            seli[it] = bi;
        }
        __syncthreads();
        if (tid < 62) mdv[tid] = fminf(mdv[tid], Dm[seli[it]*62 + tid]);
        __syncthreads();
    }
    if (tid < 5){
        int c0 = seli[tid];
        #pragma unroll
        for (int j = 0; j < 3; ++j) ccen[tid][j] = pos_emb[((size_t)b*62 + c0)*3 + j];
    }
    __syncthreads();
    if (tid < 62){
        float px = pos_emb[((size_t)b*62 + tid)*3 + 0];
        float py = pos_emb[((size_t)b*62 + tid)*3 + 1];
        float pz = pos_emb[((size_t)b*62 + tid)*3 + 2];
        int best = 0; float bd = 3.4e38f;
        #pragma unroll
        for (int t = 0; t < 5; ++t){
            float dx = px - ccen[t][0], dy = py - ccen[t][1], dz = pz - ccen[t][2];
            float d2 = dx*dx + dy*dy + dz*dz;
            if (d2 < bd){ bd = d2; best = t; }
        }
        atomicAdd(&gsums[best*3 + 0], px);
        atomicAdd(&gsums[best*3 + 1], py);
        atomicAdd(&gsums[best*3 + 2], pz);
        atomicAdd(&gcnt[best], 1.f);
    }
}

// ---------------------------------------------------------------------------
// Kernel C: pos FPS centers, center update, stable order + greedy assignment.
// 1 block x 64 threads (mostly serial on t0 — tiny).
// ---------------------------------------------------------------------------
__global__ __launch_bounds__(64) void finalize_kernel(
        const float* __restrict__ pos_emb, const float* __restrict__ gsums,
        const float* __restrict__ gcnt, int* __restrict__ assign_out)
{
    __shared__ float P[62*3];
    __shared__ float Dp[62*62];
    __shared__ float rsv[62];
    __shared__ float mdv[62];
    __shared__ int   seli[5];
    const int tid = threadIdx.x;

    if (tid < 62){
        #pragma unroll
        for (int j = 0; j < 3; ++j) P[tid*3 + j] = pos_emb[(size_t)tid*3 + j];
    }
    __syncthreads();
    if (tid < 62){
        float xi = P[tid*3], yi = P[tid*3+1], zi = P[tid*3+2];
        float s = 0.f;
        for (int j = 0; j < 62; ++j){
            float dx = xi - P[j*3], dy = yi - P[j*3+1], dz = zi - P[j*3+2];
            float d = sqrtf(dx*dx + dy*dy + dz*dz);
            Dp[tid*62 + j] = d; s += d;
        }
        rsv[tid] = s;
    }
    __syncthreads();
    if (tid == 0){
        int bi = 0; float bv = rsv[0];
        for (int i = 1; i < 62; ++i) if (rsv[i] > bv){ bv = rsv[i]; bi = i; }
        seli[0] = bi;
        for (int i = 0; i < 62; ++i) mdv[i] = Dp[bi*62 + i];
        for (int it = 1; it < 5; ++it){
            int fi = 0; float fv = mdv[0];
            for (int i = 1; i < 62; ++i) if (mdv[i] > fv){ fv = mdv[i]; fi = i; }
            seli[it] = fi;
            for (int i = 0; i < 62; ++i) mdv[i] = fminf(mdv[i], Dp[fi*62 + i]);
        }
        float cen[5][3], avg[5][3];
        for (int t = 0; t < 5; ++t)
            for (int j = 0; j < 3; ++j) cen[t][j] = P[seli[t]*3 + j];
        for (int t = 0; t < 5; ++t){
            float c = gcnt[t];
            for (int j = 0; j < 3; ++j)
                avg[t][j] = (c > 0.f) ? gsums[t*3 + j] / fmaxf(c, 1.f) : 0.f;
        }
        // matching + update
        for (int i = 0; i < 5; ++i){
            int m = 0; float bv2 = 3.4e38f;
            for (int j = 0; j < 5; ++j){
                float dx = cen[i][0]-avg[j][0], dy = cen[i][1]-avg[j][1], dz = cen[i][2]-avg[j][2];
                float d2 = dx*dx + dy*dy + dz*dz;
                if (d2 < bv2){ bv2 = d2; m = j; }
            }
            for (int j = 0; j < 3; ++j) cen[i][j] = 0.8f*cen[i][j] + 0.2f*avg[m][j];
        }
        // stable order + greedy capacity assignment
        const int sizesA[5] = {13,13,12,12,12};
        int counts[5] = {0,0,0,0,0};
        for (int i = 0; i < 62; ++i){
            float dd[5];
            for (int t = 0; t < 5; ++t){
                float dx = P[i*3]-cen[t][0], dy = P[i*3+1]-cen[t][1], dz = P[i*3+2]-cen[t][2];
                dd[t] = sqrtf(dx*dx + dy*dy + dz*dz);
            }
            int ordv[5]; bool tk[5] = {false,false,false,false,false};
            for (int s = 0; s < 5; ++s){
                int best = -1;
                for (int t = 0; t < 5; ++t)
                    if (!tk[t] && (best < 0 || dd[t] < dd[best])) best = t;
                tk[best] = true; ordv[s] = best;
            }
            int cl = ordv[0];
            for (int s = 0; s < 5; ++s){
                int t = ordv[s];
                if (counts[t] < sizesA[t]){ cl = t; break; }
            }
            counts[cl]++;
            assign_out[i] = cl;
        }
    }
}

// ---------------------------------------------------------------------------
// Kernel D: pf = relu(LN(feats @ W.T + b)). 992 blocks x 128 threads,
// 8 rows per block (weight reuse).
// ---------------------------------------------------------------------------
__global__ __launch_bounds__(128) void proj_kernel(
        const float* __restrict__ feats, const float* __restrict__ proj_w,
        const float* __restrict__ proj_b, const float* __restrict__ lng,
        const float* __restrict__ lnb, float* __restrict__ pf)
{
    __shared__ float fs[8*FDIM];
    __shared__ float scr[4];
    const int tid = threadIdx.x;
    const int row0 = blockIdx.x * 8;

    for (int i = tid; i < 8*FDIM; i += 128)
        fs[i] = feats[(size_t)row0*FDIM + i];
    __syncthreads();

    float acc[8];
    const float bias = proj_b[tid];
    #pragma unroll
    for (int g = 0; g < 8; ++g) acc[g] = bias;

    const float4* wrow = (const float4*)(proj_w + (size_t)tid*FDIM);
    for (int kc = 0; kc < 63; ++kc){
        float4 wA = wrow[2*kc], wB = wrow[2*kc+1];
        #pragma unroll
        for (int g = 0; g < 8; ++g){
            const float4* fp = (const float4*)(fs + g*FDIM + kc*8);
            float4 p = fp[0], q = fp[1];
            float s = acc[g];
            s = fmaf(p.x,wA.x,s); s = fmaf(p.y,wA.y,s); s = fmaf(p.z,wA.z,s); s = fmaf(p.w,wA.w,s);
            s = fmaf(q.x,wB.x,s); s = fmaf(q.y,wB.y,s); s = fmaf(q.z,wB.z,s); s = fmaf(q.w,wB.w,s);
            acc[g] = s;
        }
    }
    const float gl = lng[tid], bl = lnb[tid];
    #pragma unroll
    for (int g = 0; g < 8; ++g){
        float s1 = acc[g], s2 = acc[g]*acc[g];
        bred2(s1, s2, scr, tid);
        float m = s1 * (1.f/128.f);
        float var = fmaxf(s2 * (1.f/128.f) - m*m, 0.f);
        float y = (acc[g] - m) / sqrtf(var + 1e-5f);
        y = y*gl + bl;
        pf[(size_t)(row0 + g)*DM + tid] = fmaxf(y, 0.f);
    }
}

// ---------------------------------------------------------------------------
// Kernel F: token pooling + 3-layer transformer. 128 blocks x 128 threads.
// ---------------------------------------------------------------------------
__global__ __launch_bounds__(128) void former_kernel(
        const float* __restrict__ pf, const int* __restrict__ assign,
        const float* __restrict__ pos_enc,
        const float* __restrict__ Wqkv, const float* __restrict__ bqkv,
        const float* __restrict__ Wo,   const float* __restrict__ bo,
        const float* __restrict__ W1,   const float* __restrict__ b1,
        const float* __restrict__ W2,   const float* __restrict__ b2,
        const float* __restrict__ ln1g, const float* __restrict__ ln1b,
        const float* __restrict__ ln2g, const float* __restrict__ ln2b,
        float* __restrict__ out)
{
    __shared__ float h[5*128];
    __shared__ float qkvL[5*384];
    __shared__ float attL[100];
    __shared__ float oL[5*128];
    __shared__ float hidL[5*256];
    __shared__ int   asg[62];
    __shared__ float scr[4];

    const int b = blockIdx.x;
    const int d = threadIdx.x;

    if (d < 62) asg[d] = assign[d];
    __syncthreads();

    // token pooling
    {
        float a0=0,a1=0,a2=0,a3=0,a4=0;
        const float* pfb = pf + (size_t)b*62*DM + d;
        for (int c = 0; c < 62; ++c){
            float v = pfb[(size_t)c*DM];
            int a = asg[c];
            a0 += (a==0)?v:0.f; a1 += (a==1)?v:0.f; a2 += (a==2)?v:0.f;
            a3 += (a==3)?v:0.f; a4 += (a==4)?v:0.f;
        }
        h[0*128+d] = a0/13.f + pos_enc[0*128+d];
        h[1*128+d] = a1/13.f + pos_enc[1*128+d];
        h[2*128+d] = a2/12.f + pos_enc[2*128+d];
        h[3*128+d] = a3/12.f + pos_enc[3*128+d];
        h[4*128+d] = a4/12.f + pos_enc[4*128+d];
    }
    __syncthreads();

    for (int L = 0; L < 3; ++L){
        // ---- qkv ----
        const float* Wq = Wqkv + (size_t)L*384*128;
        float acc[3][5];
        #pragma unroll
        for (int rr = 0; rr < 3; ++rr){
            float bb = bqkv[L*384 + rr*128 + d];
            #pragma unroll
            for (int t = 0; t < 5; ++t) acc[rr][t] = bb;
        }
        for (int kc = 0; kc < 16; ++kc){
            float hr[5][8];
            #pragma unroll
            for (int t = 0; t < 5; ++t){
                float4 p = *(const float4*)&h[t*128 + kc*8];
                float4 q = *(const float4*)&h[t*128 + kc*8 + 4];
                hr[t][0]=p.x; hr[t][1]=p.y; hr[t][2]=p.z; hr[t][3]=p.w;
                hr[t][4]=q.x; hr[t][5]=q.y; hr[t][6]=q.z; hr[t][7]=q.w;
            }
            #pragma unroll
            for (int rr = 0; rr < 3; ++rr){
                float4 wA = *(const float4*)(Wq + ((size_t)(rr*128 + d))*128 + kc*8);
                float4 wB = *(const float4*)(Wq + ((size_t)(rr*128 + d))*128 + kc*8 + 4);
                #pragma unroll
                for (int t = 0; t < 5; ++t){
                    float s = acc[rr][t];
                    s=fmaf(hr[t][0],wA.x,s); s=fmaf(hr[t][1],wA.y,s);
                    s=fmaf(hr[t][2],wA.z,s); s=fmaf(hr[t][3],wA.w,s);
                    s=fmaf(hr[t][4],wB.x,s); s=fmaf(hr[t][5],wB.y,s);
                    s=fmaf(hr[t][6],wB.z,s); s=fmaf(hr[t][7],wB.w,s);
                    acc[rr][t] = s;
                }
            }
        }
        #pragma unroll
        for (int rr = 0; rr < 3; ++rr)
            #pragma unroll
            for (int t = 0; t < 5; ++t)
                qkvL[t*384 + rr*128 + d] = acc[rr][t];
        __syncthreads();

        // ---- scores ----
        if (d < 100){
            int hh = d/25, rem = d - hh*25, tq = rem/5, tk = rem - (rem/5)*5;
            const float* qq = &qkvL[tq*384 + hh*32];
            const float* kk = &qkvL[tk*384 + 128 + hh*32];
            float s = 0.f;
            #pragma unroll
            for (int j = 0; j < 32; ++j) s = fmaf(qq[j], kk[j], s);
            attL[d] = s * 0.17677669529663687f;   // 1/sqrt(32)
        }
        __syncthreads();
        if (d < 20){
            int hh = d/5, tq = d - hh*5;
            float* row = &attL[hh*25 + tq*5];
            float mx = row[0];
            #pragma unroll
            for (int j = 1; j < 5; ++j) mx = fmaxf(mx, row[j]);
            float sm = 0.f;
            #pragma unroll
            for (int j = 0; j < 5; ++j){ float e = expf(row[j]-mx); row[j] = e; sm += e; }
            float inv = 1.f/sm;
            #pragma unroll
            for (int j = 0; j < 5; ++j) row[j] *= inv;
        }
        __syncthreads();

        // ---- attention output ----
        {
            int hh = d >> 5;
            #pragma unroll
            for (int t = 0; t < 5; ++t){
                float s = 0.f;
                #pragma unroll
                for (int tk = 0; tk < 5; ++tk)
                    s = fmaf(attL[hh*25 + t*5 + tk], qkvL[tk*384 + 256 + d], s);
                oL[t*128 + d] = s;
            }
        }
        __syncthreads();

        // ---- out proj + residual + LN1 ----
        float val[5];
        {
            float bv = bo[L*128 + d];
            #pragma unroll
            for (int t = 0; t < 5; ++t) val[t] = bv;
            const float* WoR = Wo + ((size_t)L*128 + d)*128;
            for (int kc = 0; kc < 16; ++kc){
                float orr[5][8];
                #pragma unroll
                for (int t = 0; t < 5; ++t){
                    float4 p = *(const float4*)&oL[t*128 + kc*8];
                    float4 q = *(const float4*)&oL[t*128 + kc*8 + 4];
                    orr[t][0]=p.x; orr[t][1]=p.y; orr[t][2]=p.z; orr[t][3]=p.w;
                    orr[t][4]=q.x; orr[t][5]=q.y; orr[t][6]=q.z; orr[t][7]=q.w;
                }
                float4 wA = *(const float4*)(WoR + kc*8);
                float4 wB = *(const float4*)(WoR + kc*8 + 4);
                #pragma unroll
                for (int t = 0; t < 5; ++t){
                    float s = val[t];
                    s=fmaf(orr[t][0],wA.x,s); s=fmaf(orr[t][1],wA.y,s);
                    s=fmaf(orr[t][2],wA.z,s); s=fmaf(orr[t][3],wA.w,s);
                    s=fmaf(orr[t][4],wB.x,s); s=fmaf(orr[t][5],wB.y,s);
                    s=fmaf(orr[t][6],wB.z,s); s=fmaf(orr[t][7],wB.w,s);
                    val[t] = s;
                }
            }
            #pragma unroll
            for (int t = 0; t < 5; ++t) val[t] += h[t*128 + d];
        }
        {
            float ng = ln1g[L*128 + d], nb = ln1b[L*128 + d];
            #pragma unroll
            for (int t = 0; t < 5; ++t){
                float s1 = val[t], s2 = val[t]*val[t];
                bred2(s1, s2, scr, d);
                float m = s1*(1.f/128.f);
                float var = fmaxf(s2*(1.f/128.f) - m*m, 0.f);
                float y = (val[t] - m) / sqrtf(var + 1e-5f);
                h[t*128 + d] = y*ng + nb;
            }
        }
        __syncthreads();

        // ---- FF1 ----
        {
            float f1[2][5];
            #pragma unroll
            for (int rr = 0; rr < 2; ++rr){
                float bb = b1[L*256 + rr*128 + d];
                #pragma unroll
                for (int t = 0; t < 5; ++t) f1[rr][t] = bb;
            }
            const float* W1b = W1 + (size_t)L*256*128;
            for (int kc = 0; kc < 16; ++kc){
                float hr[5][8];
                #pragma unroll
                for (int t = 0; t < 5; ++t){
                    float4 p = *(const float4*)&h[t*128 + kc*8];
                    float4 q = *(const float4*)&h[t*128 + kc*8 + 4];
                    hr[t][0]=p.x; hr[t][1]=p.y; hr[t][2]=p.z; hr[t][3]=p.w;
                    hr[t][4]=q.x; hr[t][5]=q.y; hr[t][6]=q.z; hr[t][7]=q.w;
                }
                #pragma unroll
                for (int rr = 0; rr < 2; ++rr){
                    float4 wA = *(const float4*)(W1b + ((size_t)(rr*128 + d))*128 + kc*8);
                    float4 wB = *(const float4*)(W1b + ((size_t)(rr*128 + d))*128 + kc*8 + 4);
                    #pragma unroll
                    for (int t = 0; t < 5; ++t){
                        float s = f1[rr][t];
                        s=fmaf(hr[t][0],wA.x,s); s=fmaf(hr[t][1],wA.y,s);
                        s=fmaf(hr[t][2],wA.z,s); s=fmaf(hr[t][3],wA.w,s);
                        s=fmaf(hr[t][4],wB.x,s); s=fmaf(hr[t][5],wB.y,s);
                        s=fmaf(hr[t][6],wB.z,s); s=fmaf(hr[t][7],wB.w,s);
                        f1[rr][t] = s;
                    }
                }
            }
            #pragma unroll
            for (int rr = 0; rr < 2; ++rr)
                #pragma unroll
                for (int t = 0; t < 5; ++t)
                    hidL[t*256 + rr*128 + d] = fmaxf(f1[rr][t], 0.f);
        }
        __syncthreads();

        // ---- FF2 + residual + LN2 ----
        {
            float v2[5];
            float bv = b2[L*128 + d];
            #pragma unroll
            for (int t = 0; t < 5; ++t) v2[t] = bv;
            const float* W2R = W2 + ((size_t)L*128 + d)*256;
            for (int kc = 0; kc < 32; ++kc){
                float hr[5][8];
                #pragma unroll
                for (int t = 0; t < 5; ++t){
                    float4 p = *(const float4*)&hidL[t*256 + kc*8];
                    float4 q = *(const float4*)&hidL[t*256 + kc*8 + 4];
                    hr[t][0]=p.x; hr[t][1]=p.y; hr[t][2]=p.z; hr[t][3]=p.w;
                    hr[t][4]=q.x; hr[t][5]=q.y; hr[t][6]=q.z; hr[t][7]=q.w;
                }
                float4 wA = *(const float4*)(W2R + kc*8);
                float4 wB = *(const float4*)(W2R + kc*8 + 4);
                #pragma unroll
                for (int t = 0; t < 5; ++t){
                    float s = v2[t];
                    s=fmaf(hr[t][0],wA.x,s); s=fmaf(hr[t][1],wA.y,s);
                    s=fmaf(hr[t][2],wA.z,s); s=fmaf(hr[t][3],wA.w,s);
                    s=fmaf(hr[t][4],wB.x,s); s=fmaf(hr[t][5],wB.y,s);
                    s=fmaf(hr[t][6],wB.z,s); s=fmaf(hr[t][7],wB.w,s);
                    v2[t] = s;
                }
            }
            #pragma unroll
            for (int t = 0; t < 5; ++t) v2[t] += h[t*128 + d];
            float ng = ln2g[L*128 + d], nb = ln2b[L*128 + d];
            #pragma unroll
            for (int t = 0; t < 5; ++t){
                float s1 = v2[t], s2 = v2[t]*v2[t];
                bred2(s1, s2, scr, d);
                float m = s1*(1.f/128.f);
                float var = fmaxf(s2*(1.f/128.f) - m*m, 0.f);
                float y = (v2[t] - m) / sqrtf(var + 1e-5f);
                h[t*128 + d] = y*ng + nb;
            }
        }
        __syncthreads();
    }

    #pragma unroll
    for (int t = 0; t < 5; ++t)
        out[((size_t)b*5 + t)*128 + d] = h[t*128 + d];
}

// ---------------------------------------------------------------------------
extern "C" void kernel_launch(void* const* d_in, const int* in_sizes, int n_in,
                              void* d_out, int out_size, void* d_ws, size_t ws_size,
                              hipStream_t stream)
{
    const float* x        = (const float*)d_in[0];
    const float* pos_emb  = (const float*)d_in[1];
    const float* proj_w   = (const float*)d_in[2];
    const float* proj_b   = (const float*)d_in[3];
    const float* proj_lng = (const float*)d_in[4];
    const float* proj_lnb = (const float*)d_in[5];
    const float* pos_enc  = (const float*)d_in[6];
    const float* Wqkv     = (const float*)d_in[7];
    const float* bqkv     = (const float*)d_in[8];
    const float* Wo       = (const float*)d_in[9];
    const float* bo       = (const float*)d_in[10];
    const float* W1       = (const float*)d_in[11];
    const float* b1       = (const float*)d_in[12];
    const float* W2       = (const float*)d_in[13];
    const float* b2       = (const float*)d_in[14];
    const float* ln1g     = (const float*)d_in[15];
    const float* ln1b     = (const float*)d_in[16];
    const float* ln2g     = (const float*)d_in[17];
    const float* ln2b     = (const float*)d_in[18];

    float* ws    = (float*)d_ws;
    float* feats = ws;                              // 128*62*504
    float* pf    = feats + (size_t)N_SIG*FDIM;      // 128*62*128
    float* gsums = pf + (size_t)N_SIG*DM;           // 15
    float* gcnt  = gsums + 15;                      // 5
    int*   assign = (int*)(gcnt + 5);               // 62

    float* out = (float*)d_out;

    feat_kernel<<<1984, 256, 0, stream>>>(x, feats, gsums, gcnt);
    cluster_kernel<<<128, 256, 0, stream>>>(feats, pos_emb, gsums, gcnt);
    finalize_kernel<<<1, 64, 0, stream>>>(pos_emb, gsums, gcnt, assign);
    proj_kernel<<<992, 128, 0, stream>>>(feats, proj_w, proj_b, proj_lng, proj_lnb, pf);
    former_kernel<<<128, 128, 0, stream>>>(pf, assign, pos_enc,
        Wqkv, bqkv, Wo, bo, W1, b1, W2, b2, ln1g, ln1b, ln2g, ln2b, out);
}

// Round 3
// 931.131 us; speedup vs baseline: 1.2074x; 1.2074x over previous
//
#include <hip/hip_runtime.h>
#include <hip/hip_bf16.h>

// ===========================================================================
// EEGRCformer forward on MI355X. ALL tensors float32.
// R2: feat_kernel rework — window stride remap (bank conflicts 9-way -> ~2-3
// way), basis precomputed to global (LDS 59->36KB, occupancy 2->4 blk/CU).
// ws layout (floats): feats[128*62*504] | pf[128*62*128] | gsums[15] |
//                     gcnt[5] | assign[62 ints] | basis[45*504]
// ===========================================================================

typedef unsigned int u32;

#define N_SIG   7936          // 128*62
#define FDIM    504           // 36*14
#define DM      128

__device__ __constant__ int band_of_c[46] = {
    -1, 0,0,0, 1,1,1,1, 2,2,2,2, 3,3,3,3, 4,4,4,4,
    5,5,5,5,5,5,5,5,5,5,
    6,6,6,6,6,6,6,6,6,6,6,6,6,6,6, -1};
__device__ __constant__ float bandcnt_c[7] = {3.f,4.f,4.f,4.f,4.f,10.f,15.f};

// block reduce of (a,b) over 128 threads (2 waves); scr must be >=4 floats
static __device__ __forceinline__ void bred2(float& a, float& b, volatile float* scr, int tid){
    #pragma unroll
    for (int off = 32; off > 0; off >>= 1){
        a += __shfl_down(a, off, 64);
        b += __shfl_down(b, off, 64);
    }
    if ((tid & 63) == 0){ scr[tid>>6] = a; scr[2 + (tid>>6)] = b; }
    __syncthreads();
    a = scr[0] + scr[1];
    b = scr[2] + scr[3];
    __syncthreads();
}

// ---------------------------------------------------------------------------
// Kernel 0: precompute Hann-folded DFT basis -> global.
// Layout: bin g in 1..45 (1-based): cos row at (g-1)*504, sin row +252.
// Bin 45 and n>=250 are zeros (compute-discard padding).
// ---------------------------------------------------------------------------
__global__ __launch_bounds__(256) void basis_kernel(float* __restrict__ basis)
{
    int idx = blockIdx.x*256 + threadIdx.x;      // over 45*252
    if (idx >= 45*252) return;
    int g1 = idx / 252;           // 0..44 -> bin g1+1
    int n  = idx - g1*252;
    float vc = 0.f, vs = 0.f;
    if (g1 < 44 && n < 250){
        const float TPO = 0.025132741228718345f; // 2*pi/250
        int k = g1 + 1;
        int m = (k*n) % 250;                     // exact reduction
        float th = (float)m * TPO;
        float sn, csn; sincosf(th, &sn, &csn);
        float hw = 0.5f*(1.f - cosf((float)n * TPO));
        vc = hw*csn; vs = hw*sn;
    }
    basis[(size_t)g1*504 + n]       = vc;
    basis[(size_t)g1*504 + 252 + n] = vs;
}

// ---------------------------------------------------------------------------
// Kernel A: windowed DFT -> band PSD + DE -> per-signal z-norm -> feats
// 1984 blocks x 256 threads, 4 signals per block.
// Thread map (tid<216): kp=tid/36 (bin pair), s=(tid%36)/9, wg=tid%9;
// windows handled: {wg, wg+9, wg+18, wg+27}  (stride-9 -> bank spread).
// ---------------------------------------------------------------------------
__global__ __launch_bounds__(256) void feat_kernel(
        const float* __restrict__ x, const float* __restrict__ basis,
        float* __restrict__ feats,
        float* __restrict__ gsums, float* __restrict__ gcnt)
{
    __shared__ float xs[4*2004];     // zero-padded signal rows
    __shared__ float psum[4*36*7];   // band power sums

    const int tid = threadIdx.x;
    const int sig0 = blockIdx.x * 4;

    if (blockIdx.x == 0 && tid < 20){
        if (tid < 15) gsums[tid] = 0.f; else gcnt[tid-15] = 0.f;
    }

    for (int idx = tid; idx < 4*2004; idx += 256){
        int s = idx / 2004, n = idx - s*2004;
        float v = 0.f;
        if (n < 2000) v = x[(size_t)(sig0+s)*2000 + n];
        xs[idx] = v;
    }
    for (int i = tid; i < 4*36*7; i += 256) psum[i] = 0.f;
    __syncthreads();

    if (tid < 216){
        const int kp = tid / 36;           // 0..5 -> local bins 2kp, 2kp+1
        const int sw = tid - kp*36;
        const int s  = sw / 9;
        const int wg = sw - s*9;
        const float* xb = xs + s*2004 + 50*wg;   // + 450*w for w=0..3

        for (int cc = 0; cc < 4; ++cc){
            const int kA = 1 + cc*11 + 2*kp;     // global bin, <= 44
            // bin kA rows; bin kA+1 rows (kA+1==45 -> zero rows)
            const float4* bcA = (const float4*)(basis + (size_t)(kA-1)*504);
            const float4* bsA = (const float4*)(basis + (size_t)(kA-1)*504 + 252);
            const float4* bcB = (const float4*)(basis + (size_t)kA*504);
            const float4* bsB = (const float4*)(basis + (size_t)kA*504 + 252);

            float aca[4] = {0,0,0,0}, asa[4] = {0,0,0,0};
            float acb[4] = {0,0,0,0}, asb[4] = {0,0,0,0};

            for (int q = 0; q < 63; ++q){
                float4 ca = bcA[q], sa = bsA[q];
                float4 cb = bcB[q], sb = bsB[q];
                #pragma unroll
                for (int w = 0; w < 4; ++w){
                    const float2* xp = (const float2*)(xb + 450*w + 4*q);
                    float2 u0 = xp[0], u1 = xp[1];
                    float x0 = u0.x, x1 = u0.y, x2 = u1.x, x3 = u1.y;
                    aca[w] = fmaf(x0, ca.x, aca[w]); aca[w] = fmaf(x1, ca.y, aca[w]);
                    aca[w] = fmaf(x2, ca.z, aca[w]); aca[w] = fmaf(x3, ca.w, aca[w]);
                    asa[w] = fmaf(x0, sa.x, asa[w]); asa[w] = fmaf(x1, sa.y, asa[w]);
                    asa[w] = fmaf(x2, sa.z, asa[w]); asa[w] = fmaf(x3, sa.w, asa[w]);
                    acb[w] = fmaf(x0, cb.x, acb[w]); acb[w] = fmaf(x1, cb.y, acb[w]);
                    acb[w] = fmaf(x2, cb.z, acb[w]); acb[w] = fmaf(x3, cb.w, acb[w]);
                    asb[w] = fmaf(x0, sb.x, asb[w]); asb[w] = fmaf(x1, sb.y, asb[w]);
                    asb[w] = fmaf(x2, sb.z, asb[w]); asb[w] = fmaf(x3, sb.w, asb[w]);
                }
            }
            const int bA = band_of_c[kA];
            #pragma unroll
            for (int w = 0; w < 4; ++w){
                float pa = (aca[w]*aca[w] + asa[w]*asa[w]) * (1.0f/250.0f);
                atomicAdd(&psum[(s*36 + wg + 9*w)*7 + bA], pa);
            }
            if (kp < 5){
                const int bB = band_of_c[kA + 1];
                #pragma unroll
                for (int w = 0; w < 4; ++w){
                    float pb = (acb[w]*acb[w] + asb[w]*asb[w]) * (1.0f/250.0f);
                    atomicAdd(&psum[(s*36 + wg + 9*w)*7 + bB], pb);
                }
            }
        }
    }
    __syncthreads();

    // per-signal normalization: one wave per signal
    {
        const int s = tid >> 6, lane = tid & 63;
        float s1p=0,s2p=0,s1d=0,s2d=0;
        for (int e = lane; e < 252; e += 64){
            int bi = e % 7;
            float psd = psum[s*252 + e] / bandcnt_c[bi];
            float de  = 0.5f * logf(17.079468445347134f*psd + 1e-9f);
            s1p += psd; s2p += psd*psd; s1d += de; s2d += de*de;
        }
        #pragma unroll
        for (int off = 32; off > 0; off >>= 1){
            s1p += __shfl_down(s1p, off, 64); s2p += __shfl_down(s2p, off, 64);
            s1d += __shfl_down(s1d, off, 64); s2d += __shfl_down(s2d, off, 64);
        }
        s1p = __shfl(s1p, 0, 64); s2p = __shfl(s2p, 0, 64);
        s1d = __shfl(s1d, 0, 64); s2d = __shfl(s2d, 0, 64);
        float mp = s1p / 252.f;
        float vp = fmaxf((s2p - 252.f*mp*mp) / 251.f, 0.f);
        float sp = sqrtf(vp) + 1e-9f;
        float md = s1d / 252.f;
        float vd = fmaxf((s2d - 252.f*md*md) / 251.f, 0.f);
        float sd = sqrtf(vd) + 1e-9f;

        float* ob = feats + (size_t)(sig0 + s) * FDIM;
        for (int e = lane; e < 252; e += 64){
            int w = e / 7, bi = e - w*7;
            float psd = psum[s*252 + e] / bandcnt_c[bi];
            float de  = 0.5f * logf(17.079468445347134f*psd + 1e-9f);
            ob[w*14 + bi]     = (psd - mp) / sp;
            ob[w*14 + 7 + bi] = (de  - md) / sd;
        }
    }
}

// ---------------------------------------------------------------------------
// Kernel B: per-batch 62x62 feature distances -> FPS(5) -> temp assign ->
// atomic accumulate pos sums/counts. 128 blocks x 256 threads.
// ---------------------------------------------------------------------------
__global__ __launch_bounds__(256) void cluster_kernel(
        const float* __restrict__ feats, const float* __restrict__ pos_emb,
        float* __restrict__ gsums, float* __restrict__ gcnt)
{
    __shared__ float Fc[62*130];
    __shared__ float Dm[62*62];
    __shared__ float mdv[62];
    __shared__ float rsv[62];
    __shared__ int   seli[5];
    __shared__ float ccen[5][3];

    const int tid = threadIdx.x;
    const int b   = blockIdx.x;

    for (int i = tid; i < 3844; i += 256) Dm[i] = 0.f;
    __syncthreads();

    for (int ch = 0; ch < 4; ++ch){
        for (int i = tid; i < 62*126; i += 256){
            int r = i / 126, dc = i - r*126;
            Fc[r*130 + dc] = feats[((size_t)b*62 + r)*FDIM + ch*126 + dc];
        }
        __syncthreads();
        for (int e = tid; e < 3844; e += 256){
            int i = e / 62, j = e - i*62;
            const float2* ri = (const float2*)(Fc + i*130);
            const float2* rj = (const float2*)(Fc + j*130);
            float acc = 0.f;
            for (int t = 0; t < 63; ++t){
                float2 a = ri[t], c = rj[t];
                float d0 = a.x - c.x, d1 = a.y - c.y;
                acc = fmaf(d0, d0, acc); acc = fmaf(d1, d1, acc);
            }
            Dm[e] += acc;
        }
        __syncthreads();
    }
    for (int e = tid; e < 3844; e += 256) Dm[e] = sqrtf(Dm[e]);
    __syncthreads();

    if (tid < 62){ float s = 0.f; for (int j = 0; j < 62; ++j) s += Dm[tid*62 + j]; rsv[tid] = s; }
    __syncthreads();
    if (tid == 0){
        int bi = 0; float bv = rsv[0];
        for (int i = 1; i < 62; ++i) if (rsv[i] > bv){ bv = rsv[i]; bi = i; }
        seli[0] = bi;
    }
    __syncthreads();
    if (tid < 62) mdv[tid] = Dm[seli[0]*62 + tid];
    __syncthreads();
    for (int it = 1; it < 5; ++it){
        if (tid == 0){
            int bi = 0; float bv = mdv[0];
            for (int i = 1; i < 62; ++i) if (mdv[i] > bv){ bv = mdv[i]; bi = i; }
            seli[it] = bi;
        }
        __syncthreads();
        if (tid < 62) mdv[tid] = fminf(mdv[tid], Dm[seli[it]*62 + tid]);
        __syncthreads();
    }
    if (tid < 5){
        int c0 = seli[tid];
        #pragma unroll
        for (int j = 0; j < 3; ++j) ccen[tid][j] = pos_emb[((size_t)b*62 + c0)*3 + j];
    }
    __syncthreads();
    if (tid < 62){
        float px = pos_emb[((size_t)b*62 + tid)*3 + 0];
        float py = pos_emb[((size_t)b*62 + tid)*3 + 1];
        float pz = pos_emb[((size_t)b*62 + tid)*3 + 2];
        int best = 0; float bd = 3.4e38f;
        #pragma unroll
        for (int t = 0; t < 5; ++t){
            float dx = px - ccen[t][0], dy = py - ccen[t][1], dz = pz - ccen[t][2];
            float d2 = dx*dx + dy*dy + dz*dz;
            if (d2 < bd){ bd = d2; best = t; }
        }
        atomicAdd(&gsums[best*3 + 0], px);
        atomicAdd(&gsums[best*3 + 1], py);
        atomicAdd(&gsums[best*3 + 2], pz);
        atomicAdd(&gcnt[best], 1.f);
    }
}

// ---------------------------------------------------------------------------
// Kernel C: pos FPS centers, center update, stable order (parallel) + greedy
// assignment (serial tail). 1 block x 64 threads.
// ---------------------------------------------------------------------------
__global__ __launch_bounds__(64) void finalize_kernel(
        const float* __restrict__ pos_emb, const float* __restrict__ gsums,
        const float* __restrict__ gcnt, int* __restrict__ assign_out)
{
    __shared__ float P[62*3];
    __shared__ float Dp[62*62];
    __shared__ float rsv[62];
    __shared__ float mdv[62];
    __shared__ int   seli[5];
    __shared__ float cenS[5][3];
    __shared__ int   ordS[62][5];
    const int tid = threadIdx.x;

    if (tid < 62){
        #pragma unroll
        for (int j = 0; j < 3; ++j) P[tid*3 + j] = pos_emb[(size_t)tid*3 + j];
    }
    __syncthreads();
    if (tid < 62){
        float xi = P[tid*3], yi = P[tid*3+1], zi = P[tid*3+2];
        float s = 0.f;
        for (int j = 0; j < 62; ++j){
            float dx = xi - P[j*3], dy = yi - P[j*3+1], dz = zi - P[j*3+2];
            float d = sqrtf(dx*dx + dy*dy + dz*dz);
            Dp[tid*62 + j] = d; s += d;
        }
        rsv[tid] = s;
    }
    __syncthreads();
    if (tid == 0){
        int bi = 0; float bv = rsv[0];
        for (int i = 1; i < 62; ++i) if (rsv[i] > bv){ bv = rsv[i]; bi = i; }
        seli[0] = bi;
        for (int i = 0; i < 62; ++i) mdv[i] = Dp[bi*62 + i];
        for (int it = 1; it < 5; ++it){
            int fi = 0; float fv = mdv[0];
            for (int i = 1; i < 62; ++i) if (mdv[i] > fv){ fv = mdv[i]; fi = i; }
            seli[it] = fi;
            for (int i = 0; i < 62; ++i) mdv[i] = fminf(mdv[i], Dp[fi*62 + i]);
        }
        float cen[5][3], avg[5][3];
        for (int t = 0; t < 5; ++t)
            for (int j = 0; j < 3; ++j) cen[t][j] = P[seli[t]*3 + j];
        for (int t = 0; t < 5; ++t){
            float c = gcnt[t];
            for (int j = 0; j < 3; ++j)
                avg[t][j] = (c > 0.f) ? gsums[t*3 + j] / fmaxf(c, 1.f) : 0.f;
        }
        for (int i = 0; i < 5; ++i){
            int m = 0; float bv2 = 3.4e38f;
            for (int j = 0; j < 5; ++j){
                float dx = cen[i][0]-avg[j][0], dy = cen[i][1]-avg[j][1], dz = cen[i][2]-avg[j][2];
                float d2 = dx*dx + dy*dy + dz*dz;
                if (d2 < bv2){ bv2 = d2; m = j; }
            }
            for (int j = 0; j < 3; ++j) cenS[i][j] = 0.8f*cen[i][j] + 0.2f*avg[m][j];
        }
    }
    __syncthreads();
    if (tid < 62){
        float dd[5];
        #pragma unroll
        for (int t = 0; t < 5; ++t){
            float dx = P[tid*3]-cenS[t][0], dy = P[tid*3+1]-cenS[t][1], dz = P[tid*3+2]-cenS[t][2];
            dd[t] = sqrtf(dx*dx + dy*dy + dz*dz);
        }
        bool tk[5] = {false,false,false,false,false};
        #pragma unroll
        for (int s = 0; s < 5; ++s){
            int best = -1;
            #pragma unroll
            for (int t = 0; t < 5; ++t)
                if (!tk[t] && (best < 0 || dd[t] < dd[best])) best = t;
            tk[best] = true; ordS[tid][s] = best;
        }
    }
    __syncthreads();
    if (tid == 0){
        const int sizesA[5] = {13,13,12,12,12};
        int counts[5] = {0,0,0,0,0};
        for (int i = 0; i < 62; ++i){
            int cl = ordS[i][0];
            #pragma unroll
            for (int s = 0; s < 5; ++s){
                int t = ordS[i][s];
                if (counts[t] < sizesA[t]){ cl = t; break; }
            }
            counts[cl]++;
            assign_out[i] = cl;
        }
    }
}

// ---------------------------------------------------------------------------
// Kernel D: pf = relu(LN(feats @ W.T + b)). 992 blocks x 128 threads,
// 8 rows per block (weight reuse).
// ---------------------------------------------------------------------------
__global__ __launch_bounds__(128) void proj_kernel(
        const float* __restrict__ feats, const float* __restrict__ proj_w,
        const float* __restrict__ proj_b, const float* __restrict__ lng,
        const float* __restrict__ lnb, float* __restrict__ pf)
{
    __shared__ float fs[8*FDIM];
    __shared__ float scr[4];
    const int tid = threadIdx.x;
    const int row0 = blockIdx.x * 8;

    for (int i = tid; i < 8*FDIM; i += 128)
        fs[i] = feats[(size_t)row0*FDIM + i];
    __syncthreads();

    float acc[8];
    const float bias = proj_b[tid];
    #pragma unroll
    for (int g = 0; g < 8; ++g) acc[g] = bias;

    const float4* wrow = (const float4*)(proj_w + (size_t)tid*FDIM);
    for (int kc = 0; kc < 63; ++kc){
        float4 wA = wrow[2*kc], wB = wrow[2*kc+1];
        #pragma unroll
        for (int g = 0; g < 8; ++g){
            const float4* fp = (const float4*)(fs + g*FDIM + kc*8);
            float4 p = fp[0], q = fp[1];
            float s = acc[g];
            s = fmaf(p.x,wA.x,s); s = fmaf(p.y,wA.y,s); s = fmaf(p.z,wA.z,s); s = fmaf(p.w,wA.w,s);
            s = fmaf(q.x,wB.x,s); s = fmaf(q.y,wB.y,s); s = fmaf(q.z,wB.z,s); s = fmaf(q.w,wB.w,s);
            acc[g] = s;
        }
    }
    const float gl = lng[tid], bl = lnb[tid];
    #pragma unroll
    for (int g = 0; g < 8; ++g){
        float s1 = acc[g], s2 = acc[g]*acc[g];
        bred2(s1, s2, scr, tid);
        float m = s1 * (1.f/128.f);
        float var = fmaxf(s2 * (1.f/128.f) - m*m, 0.f);
        float y = (acc[g] - m) / sqrtf(var + 1e-5f);
        y = y*gl + bl;
        pf[(size_t)(row0 + g)*DM + tid] = fmaxf(y, 0.f);
    }
}

// ---------------------------------------------------------------------------
// Kernel F: token pooling + 3-layer transformer. 128 blocks x 128 threads.
// ---------------------------------------------------------------------------
__global__ __launch_bounds__(128) void former_kernel(
        const float* __restrict__ pf, const int* __restrict__ assign,
        const float* __restrict__ pos_enc,
        const float* __restrict__ Wqkv, const float* __restrict__ bqkv,
        const float* __restrict__ Wo,   const float* __restrict__ bo,
        const float* __restrict__ W1,   const float* __restrict__ b1,
        const float* __restrict__ W2,   const float* __restrict__ b2,
        const float* __restrict__ ln1g, const float* __restrict__ ln1b,
        const float* __restrict__ ln2g, const float* __restrict__ ln2b,
        float* __restrict__ out)
{
    __shared__ float h[5*128];
    __shared__ float qkvL[5*384];
    __shared__ float attL[100];
    __shared__ float oL[5*128];
    __shared__ float hidL[5*256];
    __shared__ int   asg[62];
    __shared__ float scr[4];

    const int b = blockIdx.x;
    const int d = threadIdx.x;

    if (d < 62) asg[d] = assign[d];
    __syncthreads();

    // token pooling
    {
        float a0=0,a1=0,a2=0,a3=0,a4=0;
        const float* pfb = pf + (size_t)b*62*DM + d;
        for (int c = 0; c < 62; ++c){
            float v = pfb[(size_t)c*DM];
            int a = asg[c];
            a0 += (a==0)?v:0.f; a1 += (a==1)?v:0.f; a2 += (a==2)?v:0.f;
            a3 += (a==3)?v:0.f; a4 += (a==4)?v:0.f;
        }
        h[0*128+d] = a0/13.f + pos_enc[0*128+d];
        h[1*128+d] = a1/13.f + pos_enc[1*128+d];
        h[2*128+d] = a2/12.f + pos_enc[2*128+d];
        h[3*128+d] = a3/12.f + pos_enc[3*128+d];
        h[4*128+d] = a4/12.f + pos_enc[4*128+d];
    }
    __syncthreads();

    for (int L = 0; L < 3; ++L){
        // ---- qkv ----
        const float* Wq = Wqkv + (size_t)L*384*128;
        float acc[3][5];
        #pragma unroll
        for (int rr = 0; rr < 3; ++rr){
            float bb = bqkv[L*384 + rr*128 + d];
            #pragma unroll
            for (int t = 0; t < 5; ++t) acc[rr][t] = bb;
        }
        for (int kc = 0; kc < 16; ++kc){
            float hr[5][8];
            #pragma unroll
            for (int t = 0; t < 5; ++t){
                float4 p = *(const float4*)&h[t*128 + kc*8];
                float4 q = *(const float4*)&h[t*128 + kc*8 + 4];
                hr[t][0]=p.x; hr[t][1]=p.y; hr[t][2]=p.z; hr[t][3]=p.w;
                hr[t][4]=q.x; hr[t][5]=q.y; hr[t][6]=q.z; hr[t][7]=q.w;
            }
            #pragma unroll
            for (int rr = 0; rr < 3; ++rr){
                float4 wA = *(const float4*)(Wq + ((size_t)(rr*128 + d))*128 + kc*8);
                float4 wB = *(const float4*)(Wq + ((size_t)(rr*128 + d))*128 + kc*8 + 4);
                #pragma unroll
                for (int t = 0; t < 5; ++t){
                    float s = acc[rr][t];
                    s=fmaf(hr[t][0],wA.x,s); s=fmaf(hr[t][1],wA.y,s);
                    s=fmaf(hr[t][2],wA.z,s); s=fmaf(hr[t][3],wA.w,s);
                    s=fmaf(hr[t][4],wB.x,s); s=fmaf(hr[t][5],wB.y,s);
                    s=fmaf(hr[t][6],wB.z,s); s=fmaf(hr[t][7],wB.w,s);
                    acc[rr][t] = s;
                }
            }
        }
        #pragma unroll
        for (int rr = 0; rr < 3; ++rr)
            #pragma unroll
            for (int t = 0; t < 5; ++t)
                qkvL[t*384 + rr*128 + d] = acc[rr][t];
        __syncthreads();

        // ---- scores ----
        if (d < 100){
            int hh = d/25, rem = d - hh*25, tq = rem/5, tk = rem - (rem/5)*5;
            const float* qq = &qkvL[tq*384 + hh*32];
            const float* kk = &qkvL[tk*384 + 128 + hh*32];
            float s = 0.f;
            #pragma unroll
            for (int j = 0; j < 32; ++j) s = fmaf(qq[j], kk[j], s);
            attL[d] = s * 0.17677669529663687f;   // 1/sqrt(32)
        }
        __syncthreads();
        if (d < 20){
            int hh = d/5, tq = d - hh*5;
            float* row = &attL[hh*25 + tq*5];
            float mx = row[0];
            #pragma unroll
            for (int j = 1; j < 5; ++j) mx = fmaxf(mx, row[j]);
            float sm = 0.f;
            #pragma unroll
            for (int j = 0; j < 5; ++j){ float e = expf(row[j]-mx); row[j] = e; sm += e; }
            float inv = 1.f/sm;
            #pragma unroll
            for (int j = 0; j < 5; ++j) row[j] *= inv;
        }
        __syncthreads();

        // ---- attention output ----
        {
            int hh = d >> 5;
            #pragma unroll
            for (int t = 0; t < 5; ++t){
                float s = 0.f;
                #pragma unroll
                for (int tk = 0; tk < 5; ++tk)
                    s = fmaf(attL[hh*25 + t*5 + tk], qkvL[tk*384 + 256 + d], s);
                oL[t*128 + d] = s;
            }
        }
        __syncthreads();

        // ---- out proj + residual + LN1 ----
        float val[5];
        {
            float bv = bo[L*128 + d];
            #pragma unroll
            for (int t = 0; t < 5; ++t) val[t] = bv;
            const float* WoR = Wo + ((size_t)L*128 + d)*128;
            for (int kc = 0; kc < 16; ++kc){
                float orr[5][8];
                #pragma unroll
                for (int t = 0; t < 5; ++t){
                    float4 p = *(const float4*)&oL[t*128 + kc*8];
                    float4 q = *(const float4*)&oL[t*128 + kc*8 + 4];
                    orr[t][0]=p.x; orr[t][1]=p.y; orr[t][2]=p.z; orr[t][3]=p.w;
                    orr[t][4]=q.x; orr[t][5]=q.y; orr[t][6]=q.z; orr[t][7]=q.w;
                }
                float4 wA = *(const float4*)(WoR + kc*8);
                float4 wB = *(const float4*)(WoR + kc*8 + 4);
                #pragma unroll
                for (int t = 0; t < 5; ++t){
                    float s = val[t];
                    s=fmaf(orr[t][0],wA.x,s); s=fmaf(orr[t][1],wA.y,s);
                    s=fmaf(orr[t][2],wA.z,s); s=fmaf(orr[t][3],wA.w,s);
                    s=fmaf(orr[t][4],wB.x,s); s=fmaf(orr[t][5],wB.y,s);
                    s=fmaf(orr[t][6],wB.z,s); s=fmaf(orr[t][7],wB.w,s);
                    val[t] = s;
                }
            }
            #pragma unroll
            for (int t = 0; t < 5; ++t) val[t] += h[t*128 + d];
        }
        {
            float ng = ln1g[L*128 + d], nb = ln1b[L*128 + d];
            #pragma unroll
            for (int t = 0; t < 5; ++t){
                float s1 = val[t], s2 = val[t]*val[t];
                bred2(s1, s2, scr, d);
                float m = s1*(1.f/128.f);
                float var = fmaxf(s2*(1.f/128.f) - m*m, 0.f);
                float y = (val[t] - m) / sqrtf(var + 1e-5f);
                h[t*128 + d] = y*ng + nb;
            }
        }
        __syncthreads();

        // ---- FF1 ----
        {
            float f1[2][5];
            #pragma unroll
            for (int rr = 0; rr < 2; ++rr){
                float bb = b1[L*256 + rr*128 + d];
                #pragma unroll
                for (int t = 0; t < 5; ++t) f1[rr][t] = bb;
            }
            const float* W1b = W1 + (size_t)L*256*128;
            for (int kc = 0; kc < 16; ++kc){
                float hr[5][8];
                #pragma unroll
                for (int t = 0; t < 5; ++t){
                    float4 p = *(const float4*)&h[t*128 + kc*8];
                    float4 q = *(const float4*)&h[t*128 + kc*8 + 4];
                    hr[t][0]=p.x; hr[t][1]=p.y; hr[t][2]=p.z; hr[t][3]=p.w;
                    hr[t][4]=q.x; hr[t][5]=q.y; hr[t][6]=q.z; hr[t][7]=q.w;
                }
                #pragma unroll
                for (int rr = 0; rr < 2; ++rr){
                    float4 wA = *(const float4*)(W1b + ((size_t)(rr*128 + d))*128 + kc*8);
                    float4 wB = *(const float4*)(W1b + ((size_t)(rr*128 + d))*128 + kc*8 + 4);
                    #pragma unroll
                    for (int t = 0; t < 5; ++t){
                        float s = f1[rr][t];
                        s=fmaf(hr[t][0],wA.x,s); s=fmaf(hr[t][1],wA.y,s);
                        s=fmaf(hr[t][2],wA.z,s); s=fmaf(hr[t][3],wA.w,s);
                        s=fmaf(hr[t][4],wB.x,s); s=fmaf(hr[t][5],wB.y,s);
                        s=fmaf(hr[t][6],wB.z,s); s=fmaf(hr[t][7],wB.w,s);
                        f1[rr][t] = s;
                    }
                }
            }
            #pragma unroll
            for (int rr = 0; rr < 2; ++rr)
                #pragma unroll
                for (int t = 0; t < 5; ++t)
                    hidL[t*256 + rr*128 + d] = fmaxf(f1[rr][t], 0.f);
        }
        __syncthreads();

        // ---- FF2 + residual + LN2 ----
        {
            float v2[5];
            float bv = b2[L*128 + d];
            #pragma unroll
            for (int t = 0; t < 5; ++t) v2[t] = bv;
            const float* W2R = W2 + ((size_t)L*128 + d)*256;
            for (int kc = 0; kc < 32; ++kc){
                float hr[5][8];
                #pragma unroll
                for (int t = 0; t < 5; ++t){
                    float4 p = *(const float4*)&hidL[t*256 + kc*8];
                    float4 q = *(const float4*)&hidL[t*256 + kc*8 + 4];
                    hr[t][0]=p.x; hr[t][1]=p.y; hr[t][2]=p.z; hr[t][3]=p.w;
                    hr[t][4]=q.x; hr[t][5]=q.y; hr[t][6]=q.z; hr[t][7]=q.w;
                }
                float4 wA = *(const float4*)(W2R + kc*8);
                float4 wB = *(const float4*)(W2R + kc*8 + 4);
                #pragma unroll
                for (int t = 0; t < 5; ++t){
                    float s = v2[t];
                    s=fmaf(hr[t][0],wA.x,s); s=fmaf(hr[t][1],wA.y,s);
                    s=fmaf(hr[t][2],wA.z,s); s=fmaf(hr[t][3],wA.w,s);
                    s=fmaf(hr[t][4],wB.x,s); s=fmaf(hr[t][5],wB.y,s);
                    s=fmaf(hr[t][6],wB.z,s); s=fmaf(hr[t][7],wB.w,s);
                    v2[t] = s;
                }
            }
            #pragma unroll
            for (int t = 0; t < 5; ++t) v2[t] += h[t*128 + d];
            float ng = ln2g[L*128 + d], nb = ln2b[L*128 + d];
            #pragma unroll
            for (int t = 0; t < 5; ++t){
                float s1 = v2[t], s2 = v2[t]*v2[t];
                bred2(s1, s2, scr, d);
                float m = s1*(1.f/128.f);
                float var = fmaxf(s2*(1.f/128.f) - m*m, 0.f);
                float y = (v2[t] - m) / sqrtf(var + 1e-5f);
                h[t*128 + d] = y*ng + nb;
            }
        }
        __syncthreads();
    }

    #pragma unroll
    for (int t = 0; t < 5; ++t)
        out[((size_t)b*5 + t)*128 + d] = h[t*128 + d];
}

// ---------------------------------------------------------------------------
extern "C" void kernel_launch(void* const* d_in, const int* in_sizes, int n_in,
                              void* d_out, int out_size, void* d_ws, size_t ws_size,
                              hipStream_t stream)
{
    const float* x        = (const float*)d_in[0];
    const float* pos_emb  = (const float*)d_in[1];
    const float* proj_w   = (const float*)d_in[2];
    const float* proj_b   = (const float*)d_in[3];
    const float* proj_lng = (const float*)d_in[4];
    const float* proj_lnb = (const float*)d_in[5];
    const float* pos_enc  = (const float*)d_in[6];
    const float* Wqkv     = (const float*)d_in[7];
    const float* bqkv     = (const float*)d_in[8];
    const float* Wo       = (const float*)d_in[9];
    const float* bo       = (const float*)d_in[10];
    const float* W1       = (const float*)d_in[11];
    const float* b1       = (const float*)d_in[12];
    const float* W2       = (const float*)d_in[13];
    const float* b2       = (const float*)d_in[14];
    const float* ln1g     = (const float*)d_in[15];
    const float* ln1b     = (const float*)d_in[16];
    const float* ln2g     = (const float*)d_in[17];
    const float* ln2b     = (const float*)d_in[18];

    float* ws    = (float*)d_ws;
    float* feats = ws;                              // 128*62*504
    float* pf    = feats + (size_t)N_SIG*FDIM;      // 128*62*128
    float* gsums = pf + (size_t)N_SIG*DM;           // 15
    float* gcnt  = gsums + 15;                      // 5
    int*   assign = (int*)(gcnt + 5);               // 62
    float* basis = (float*)(assign + 64);           // 45*504

    float* out = (float*)d_out;

    basis_kernel<<<45, 256, 0, stream>>>(basis);
    feat_kernel<<<1984, 256, 0, stream>>>(x, basis, feats, gsums, gcnt);
    cluster_kernel<<<128, 256, 0, stream>>>(feats, pos_emb, gsums, gcnt);
    finalize_kernel<<<1, 64, 0, stream>>>(pos_emb, gsums, gcnt, assign);
    proj_kernel<<<992, 128, 0, stream>>>(feats, proj_w, proj_b, proj_lng, proj_lnb, pf);
    former_kernel<<<128, 128, 0, stream>>>(pf, assign, pos_enc,
        Wqkv, bqkv, Wo, bo, W1, b1, W2, b2, ln1g, ln1b, ln2g, ln2b, out);
}